// Round 1
// baseline (750.779 us; speedup 1.0000x reference)
//
#include <hip/hip_runtime.h>

#define IN_DIM 18
#define HID 64
#define EMB 32

// ---------------- degree / normalization ----------------

__global__ void k_init_deg(int* __restrict__ deg, int n) {
    int i = blockIdx.x * 256 + threadIdx.x;
    if (i < n) deg[i] = 1;   // self-loop
}

__global__ void k_count(const int* __restrict__ dst, int* __restrict__ deg, int e) {
    int i = blockIdx.x * 256 + threadIdx.x;
    if (i < e) atomicAdd(&deg[dst[i]], 1);
}

__global__ void k_dis(const int* __restrict__ deg, float* __restrict__ dis, int n) {
    int i = blockIdx.x * 256 + threadIdx.x;
    if (i < n) dis[i] = rsqrtf((float)deg[i]);
}

// ---------------- exclusive scan of counts (deg-1) -> row_ptr ----------------

__global__ void k_scanA(const int* __restrict__ deg, int* __restrict__ row_ptr,
                        int* __restrict__ blksums, int n) {
    __shared__ int s[1024];
    int tid = threadIdx.x;
    int i = blockIdx.x * 1024 + tid;
    int v = (i < n) ? (deg[i] - 1) : 0;
    s[tid] = v;
    __syncthreads();
    for (int off = 1; off < 1024; off <<= 1) {
        int t = (tid >= off) ? s[tid - off] : 0;
        __syncthreads();
        s[tid] += t;
        __syncthreads();
    }
    if (i < n) row_ptr[i] = s[tid] - v;       // exclusive within block
    if (tid == 1023) blksums[blockIdx.x] = s[1023];
}

__global__ void k_scanB(const int* __restrict__ blksums, int* __restrict__ blkoffs, int nb) {
    __shared__ int s[1024];
    int tid = threadIdx.x;
    int v = (tid < nb) ? blksums[tid] : 0;
    s[tid] = v;
    __syncthreads();
    for (int off = 1; off < 1024; off <<= 1) {
        int t = (tid >= off) ? s[tid - off] : 0;
        __syncthreads();
        s[tid] += t;
        __syncthreads();
    }
    if (tid < nb) blkoffs[tid] = s[tid] - v;  // exclusive
}

__global__ void k_scanC(int* __restrict__ row_ptr, const int* __restrict__ blkoffs,
                        int* __restrict__ write_ptr, int n) {
    int i = blockIdx.x * 1024 + threadIdx.x;
    if (i < n) {
        int r = row_ptr[i] + blkoffs[blockIdx.x];
        row_ptr[i] = r;
        write_ptr[i] = r;
    }
}

// ---------------- CSR fill ----------------

__global__ void k_fill(const int* __restrict__ src, const int* __restrict__ dst,
                       int* __restrict__ write_ptr, int* __restrict__ adj, int e) {
    int i = blockIdx.x * 256 + threadIdx.x;
    if (i < e) {
        int d = dst[i];
        int slot = atomicAdd(&write_ptr[d], 1);
        adj[slot] = src[i];
    }
}

// ---------------- layer GEMMs (dense, tiny K) ----------------

// hn[i][f] = (x[i,:] @ W1[:,f]) * dis[i]
__global__ void k_gemm1(const float* __restrict__ x, const float* __restrict__ W1,
                        const float* __restrict__ dis, float* __restrict__ hn, int n) {
    __shared__ float w[IN_DIM * HID];
    for (int t = threadIdx.x; t < IN_DIM * HID; t += 256) w[t] = W1[t];
    __syncthreads();
    int gid = blockIdx.x * 256 + threadIdx.x;
    int i = gid >> 6, f = gid & 63;
    if (i >= n) return;
    const float* xr = x + (size_t)i * IN_DIM;
    float acc = 0.f;
#pragma unroll
    for (int k = 0; k < IN_DIM; ++k) acc += xr[k] * w[k * HID + f];
    hn[(size_t)i * HID + f] = acc * dis[i];
}

// hn2[i][g] = (h[i,:] @ W2[:,g]) * dis[i]
__global__ void k_gemm2(const float* __restrict__ h, const float* __restrict__ W2,
                        const float* __restrict__ dis, float* __restrict__ hn2, int n) {
    __shared__ float w[HID * EMB];
    for (int t = threadIdx.x; t < HID * EMB; t += 256) w[t] = W2[t];
    __syncthreads();
    int gid = blockIdx.x * 256 + threadIdx.x;
    int i = gid >> 5, g = gid & 31;
    if (i >= n) return;
    const float* hr = h + (size_t)i * HID;
    float acc = 0.f;
#pragma unroll
    for (int k = 0; k < HID; ++k) acc += hr[k] * w[k * EMB + g];
    hn2[(size_t)i * EMB + g] = acc * dis[i];
}

// ---------------- aggregation (gather over CSR) ----------------

// h[i][f] = relu( dis[i]*(hn[i][f] + sum_{j in in(i)} hn[j][f]) + b1[f] )
__global__ void k_agg1(const float* __restrict__ hn, const int* __restrict__ row_ptr,
                       const int* __restrict__ deg, const int* __restrict__ adj,
                       const float* __restrict__ dis, const float* __restrict__ b1,
                       float* __restrict__ h, int n) {
    int node = blockIdx.x * 4 + (threadIdx.x >> 6);
    if (node >= n) return;
    int lane = threadIdx.x & 63;
    float acc = hn[(size_t)node * HID + lane];    // self-loop term
    int beg = row_ptr[node];
    int cnt = deg[node] - 1;
    const int* a = adj + beg;
    int k = 0;
    for (; k + 4 <= cnt; k += 4) {
        int j0 = a[k], j1 = a[k + 1], j2 = a[k + 2], j3 = a[k + 3];
        acc += hn[(size_t)j0 * HID + lane];
        acc += hn[(size_t)j1 * HID + lane];
        acc += hn[(size_t)j2 * HID + lane];
        acc += hn[(size_t)j3 * HID + lane];
    }
    for (; k < cnt; ++k) acc += hn[(size_t)a[k] * HID + lane];
    float hv = dis[node] * acc + b1[lane];
    h[(size_t)node * HID + lane] = hv > 0.f ? hv : 0.f;
}

// z[i][g] = dis[i]*(hn2[i][g] + sum_j hn2[j][g]) + b2[g]
__global__ void k_agg2(const float* __restrict__ hn2, const int* __restrict__ row_ptr,
                       const int* __restrict__ deg, const int* __restrict__ adj,
                       const float* __restrict__ dis, const float* __restrict__ b2,
                       float* __restrict__ z, int n) {
    int node = blockIdx.x * 4 + (threadIdx.x >> 6);
    if (node >= n) return;
    int lane = threadIdx.x & 63;
    int g = lane & 31;
    int half = lane >> 5;
    float acc = 0.f;
    int beg = row_ptr[node];
    int cnt = deg[node] - 1;
    const int* a = adj + beg;
    for (int k = half; k < cnt; k += 2) acc += hn2[(size_t)a[k] * EMB + g];
    acc += __shfl_down(acc, 32);
    if (half == 0) {
        acc += hn2[(size_t)node * EMB + g];       // self-loop
        z[(size_t)node * EMB + g] = dis[node] * acc + b2[g];
    }
}

// ---------------- pair head ----------------

__global__ void k_head(const float* __restrict__ z, const int* __restrict__ tg,
                       const float* __restrict__ Wo, const float* __restrict__ bo,
                       float* __restrict__ out, int btot) {
    int i = blockIdx.x * 256 + threadIdx.x;
    if (i >= btot) return;
    int t0 = tg[i], t1 = tg[btot + i];
    const float* z0 = z + (size_t)t0 * EMB;
    const float* z1 = z + (size_t)t1 * EMB;
    float acc = 0.f;
#pragma unroll
    for (int g = 0; g < EMB; ++g) acc += z0[g] * z1[g] * Wo[g];
    out[i] = acc + bo[0];
}

// ---------------- launch ----------------

extern "C" void kernel_launch(void* const* d_in, const int* in_sizes, int n_in,
                              void* d_out, int out_size, void* d_ws, size_t ws_size,
                              hipStream_t stream) {
    const float* x  = (const float*)d_in[0];
    const int*   ei = (const int*)d_in[1];
    const int*   tg = (const int*)d_in[2];
    const float* W1 = (const float*)d_in[3];
    const float* b1 = (const float*)d_in[4];
    const float* W2 = (const float*)d_in[5];
    const float* b2 = (const float*)d_in[6];
    const float* Wo = (const float*)d_in[7];
    const float* bo = (const float*)d_in[8];
    float* out = (float*)d_out;

    int n = in_sizes[0] / IN_DIM;
    int e = in_sizes[1] / 2;
    int b = in_sizes[2] / 2;
    const int* src = ei;
    const int* dst = ei + e;

    char* ws = (char*)d_ws;
    size_t off = 0;
    auto alloc = [&](size_t bytes) -> char* {
        char* p = ws + off;
        off += (bytes + 255) & ~(size_t)255;
        return p;
    };
    int*   deg       = (int*)alloc((size_t)n * 4);
    int*   row_ptr   = (int*)alloc((size_t)n * 4);
    int*   write_ptr = (int*)alloc((size_t)n * 4);
    int*   blksums   = (int*)alloc(1024 * 4);
    int*   blkoffs   = (int*)alloc(1024 * 4);
    float* dis       = (float*)alloc((size_t)n * 4);
    int*   adj       = (int*)alloc((size_t)e * 4);
    float* bufA      = (float*)alloc((size_t)n * HID * 4);  // hn, then hn2
    float* bufB      = (float*)alloc((size_t)n * HID * 4);  // h,  then z

    int nb1024 = (n + 1023) / 1024;

    k_init_deg<<<(n + 255) / 256, 256, 0, stream>>>(deg, n);
    k_count<<<(e + 255) / 256, 256, 0, stream>>>(dst, deg, e);
    k_dis<<<(n + 255) / 256, 256, 0, stream>>>(deg, dis, n);

    k_scanA<<<nb1024, 1024, 0, stream>>>(deg, row_ptr, blksums, n);
    k_scanB<<<1, 1024, 0, stream>>>(blksums, blkoffs, nb1024);
    k_scanC<<<nb1024, 1024, 0, stream>>>(row_ptr, blkoffs, write_ptr, n);

    k_fill<<<(e + 255) / 256, 256, 0, stream>>>(src, dst, write_ptr, adj, e);

    k_gemm1<<<((size_t)n * HID + 255) / 256, 256, 0, stream>>>(x, W1, dis, bufA, n);
    k_agg1<<<(n + 3) / 4, 256, 0, stream>>>(bufA, row_ptr, deg, adj, dis, b1, bufB, n);
    k_gemm2<<<((size_t)n * EMB + 255) / 256, 256, 0, stream>>>(bufB, W2, dis, bufA, n);
    k_agg2<<<(n + 3) / 4, 256, 0, stream>>>(bufA, row_ptr, deg, adj, dis, b2, bufB, n);

    k_head<<<(b + 255) / 256, 256, 0, stream>>>(bufB, tg, Wo, bo, out, b);
}

// Round 2
// 624.170 us; speedup vs baseline: 1.2028x; 1.2028x over previous
//
#include <hip/hip_runtime.h>

#define IN_DIM 18
#define HID 64
#define EMB 32
#define NGROUP 8   // XCD count; blockIdx.x & 7 ~ XCD id (heuristic, speed-only)

// ---------------- degree / normalization ----------------

__global__ void k_init_deg(int* __restrict__ deg, int n) {
    int i = blockIdx.x * 256 + threadIdx.x;
    if (i < n) deg[i] = 1;   // self-loop
}

// XCD-partitioned histogram: group g only counts dst in [lo,hi) so deg lines
// stay resident in a single XCD's L2 (no cross-XCD dirty-line ping).
__global__ void k_count_part(const int* __restrict__ dst, int* __restrict__ deg,
                             int e, int nrange, int n) {
    int g  = blockIdx.x & (NGROUP - 1);
    int lo = g * nrange;
    int hi = min(n, lo + nrange);
    int bid  = blockIdx.x >> 3;
    int nblk = gridDim.x >> 3;
    int i0   = (bid * 256 + threadIdx.x) * 4;
    int step = nblk * 256 * 4;
    for (int i = i0; i < e; i += step) {
        if (i + 4 <= e) {
            int4 d4 = *(const int4*)(dst + i);
            if (d4.x >= lo && d4.x < hi) atomicAdd(&deg[d4.x], 1);
            if (d4.y >= lo && d4.y < hi) atomicAdd(&deg[d4.y], 1);
            if (d4.z >= lo && d4.z < hi) atomicAdd(&deg[d4.z], 1);
            if (d4.w >= lo && d4.w < hi) atomicAdd(&deg[d4.w], 1);
        } else {
            for (int k = i; k < e; ++k) {
                int d = dst[k];
                if (d >= lo && d < hi) atomicAdd(&deg[d], 1);
            }
        }
    }
}

__global__ void k_dis(const int* __restrict__ deg, float* __restrict__ dis, int n) {
    int i = blockIdx.x * 256 + threadIdx.x;
    if (i < n) dis[i] = rsqrtf((float)deg[i]);
}

// ---------------- exclusive scan of counts (deg-1) -> row_ptr ----------------

__global__ void k_scanA(const int* __restrict__ deg, int* __restrict__ row_ptr,
                        int* __restrict__ blksums, int n) {
    __shared__ int s[1024];
    int tid = threadIdx.x;
    int i = blockIdx.x * 1024 + tid;
    int v = (i < n) ? (deg[i] - 1) : 0;
    s[tid] = v;
    __syncthreads();
    for (int off = 1; off < 1024; off <<= 1) {
        int t = (tid >= off) ? s[tid - off] : 0;
        __syncthreads();
        s[tid] += t;
        __syncthreads();
    }
    if (i < n) row_ptr[i] = s[tid] - v;       // exclusive within block
    if (tid == 1023) blksums[blockIdx.x] = s[1023];
}

__global__ void k_scanB(const int* __restrict__ blksums, int* __restrict__ blkoffs, int nb) {
    __shared__ int s[1024];
    int tid = threadIdx.x;
    int v = (tid < nb) ? blksums[tid] : 0;
    s[tid] = v;
    __syncthreads();
    for (int off = 1; off < 1024; off <<= 1) {
        int t = (tid >= off) ? s[tid - off] : 0;
        __syncthreads();
        s[tid] += t;
        __syncthreads();
    }
    if (tid < nb) blkoffs[tid] = s[tid] - v;  // exclusive
}

__global__ void k_scanC(int* __restrict__ row_ptr, const int* __restrict__ blkoffs,
                        int* __restrict__ write_ptr, int n) {
    int i = blockIdx.x * 1024 + threadIdx.x;
    if (i < n) {
        int r = row_ptr[i] + blkoffs[blockIdx.x];
        row_ptr[i] = r;
        write_ptr[i] = r;
    }
}

// ---------------- CSR fill (XCD-partitioned) ----------------

// Group g fills only adj slots for dst in [lo,hi): that ~1.6MB adj slice plus
// its write_ptr counters are touched by one XCD only -> L2 merges the 4B
// scatters, writeback = adj size instead of 15x amplified.
__global__ void k_fill_part(const int* __restrict__ src, const int* __restrict__ dst,
                            int* __restrict__ write_ptr, int* __restrict__ adj,
                            int e, int nrange, int n) {
    int g  = blockIdx.x & (NGROUP - 1);
    int lo = g * nrange;
    int hi = min(n, lo + nrange);
    int bid  = blockIdx.x >> 3;
    int nblk = gridDim.x >> 3;
    int i0   = (bid * 256 + threadIdx.x) * 4;
    int step = nblk * 256 * 4;
    for (int i = i0; i < e; i += step) {
        if (i + 4 <= e) {
            int4 d4 = *(const int4*)(dst + i);
            if (d4.x >= lo && d4.x < hi) { int slot = atomicAdd(&write_ptr[d4.x], 1); adj[slot] = src[i];     }
            if (d4.y >= lo && d4.y < hi) { int slot = atomicAdd(&write_ptr[d4.y], 1); adj[slot] = src[i + 1]; }
            if (d4.z >= lo && d4.z < hi) { int slot = atomicAdd(&write_ptr[d4.z], 1); adj[slot] = src[i + 2]; }
            if (d4.w >= lo && d4.w < hi) { int slot = atomicAdd(&write_ptr[d4.w], 1); adj[slot] = src[i + 3]; }
        } else {
            for (int k = i; k < e; ++k) {
                int d = dst[k];
                if (d >= lo && d < hi) { int slot = atomicAdd(&write_ptr[d], 1); adj[slot] = src[k]; }
            }
        }
    }
}

// ---------------- layer GEMMs (dense, tiny K) ----------------

// hn[i][f] = (x[i,:] @ W1[:,f]) * dis[i]
__global__ void k_gemm1(const float* __restrict__ x, const float* __restrict__ W1,
                        const float* __restrict__ dis, float* __restrict__ hn, int n) {
    __shared__ float w[IN_DIM * HID];
    for (int t = threadIdx.x; t < IN_DIM * HID; t += 256) w[t] = W1[t];
    __syncthreads();
    int gid = blockIdx.x * 256 + threadIdx.x;
    int i = gid >> 6, f = gid & 63;
    if (i >= n) return;
    const float* xr = x + (size_t)i * IN_DIM;
    float acc = 0.f;
#pragma unroll
    for (int k = 0; k < IN_DIM; ++k) acc += xr[k] * w[k * HID + f];
    hn[(size_t)i * HID + f] = acc * dis[i];
}

// hn2[i][g] = (h[i,:] @ W2[:,g]) * dis[i]
__global__ void k_gemm2(const float* __restrict__ h, const float* __restrict__ W2,
                        const float* __restrict__ dis, float* __restrict__ hn2, int n) {
    __shared__ float w[HID * EMB];
    for (int t = threadIdx.x; t < HID * EMB; t += 256) w[t] = W2[t];
    __syncthreads();
    int gid = blockIdx.x * 256 + threadIdx.x;
    int i = gid >> 5, g = gid & 31;
    if (i >= n) return;
    const float* hr = h + (size_t)i * HID;
    float acc = 0.f;
#pragma unroll
    for (int k = 0; k < HID; ++k) acc += hr[k] * w[k * EMB + g];
    hn2[(size_t)i * EMB + g] = acc * dis[i];
}

// ---------------- aggregation (gather over CSR) ----------------

// h[i][f] = relu( dis[i]*(hn[i][f] + sum_{j in in(i)} hn[j][f]) + b1[f] )
__global__ void k_agg1(const float* __restrict__ hn, const int* __restrict__ row_ptr,
                       const int* __restrict__ deg, const int* __restrict__ adj,
                       const float* __restrict__ dis, const float* __restrict__ b1,
                       float* __restrict__ h, int n) {
    int node = blockIdx.x * 4 + (threadIdx.x >> 6);
    if (node >= n) return;
    int lane = threadIdx.x & 63;
    float acc = hn[(size_t)node * HID + lane];    // self-loop term
    int beg = row_ptr[node];
    int cnt = deg[node] - 1;
    const int* a = adj + beg;
    int k = 0;
    for (; k + 4 <= cnt; k += 4) {
        int j0 = a[k], j1 = a[k + 1], j2 = a[k + 2], j3 = a[k + 3];
        acc += hn[(size_t)j0 * HID + lane];
        acc += hn[(size_t)j1 * HID + lane];
        acc += hn[(size_t)j2 * HID + lane];
        acc += hn[(size_t)j3 * HID + lane];
    }
    for (; k < cnt; ++k) acc += hn[(size_t)a[k] * HID + lane];
    float hv = dis[node] * acc + b1[lane];
    h[(size_t)node * HID + lane] = hv > 0.f ? hv : 0.f;
}

// z[i][g] = dis[i]*(hn2[i][g] + sum_j hn2[j][g]) + b2[g]
__global__ void k_agg2(const float* __restrict__ hn2, const int* __restrict__ row_ptr,
                       const int* __restrict__ deg, const int* __restrict__ adj,
                       const float* __restrict__ dis, const float* __restrict__ b2,
                       float* __restrict__ z, int n) {
    int node = blockIdx.x * 4 + (threadIdx.x >> 6);
    if (node >= n) return;
    int lane = threadIdx.x & 63;
    int g = lane & 31;
    int half = lane >> 5;
    float acc = 0.f;
    int beg = row_ptr[node];
    int cnt = deg[node] - 1;
    const int* a = adj + beg;
    for (int k = half; k < cnt; k += 2) acc += hn2[(size_t)a[k] * EMB + g];
    acc += __shfl_down(acc, 32);
    if (half == 0) {
        acc += hn2[(size_t)node * EMB + g];       // self-loop
        z[(size_t)node * EMB + g] = dis[node] * acc + b2[g];
    }
}

// ---------------- pair head ----------------

__global__ void k_head(const float* __restrict__ z, const int* __restrict__ tg,
                       const float* __restrict__ Wo, const float* __restrict__ bo,
                       float* __restrict__ out, int btot) {
    int i = blockIdx.x * 256 + threadIdx.x;
    if (i >= btot) return;
    int t0 = tg[i], t1 = tg[btot + i];
    const float* z0 = z + (size_t)t0 * EMB;
    const float* z1 = z + (size_t)t1 * EMB;
    float acc = 0.f;
#pragma unroll
    for (int g = 0; g < EMB; ++g) acc += z0[g] * z1[g] * Wo[g];
    out[i] = acc + bo[0];
}

// ---------------- launch ----------------

extern "C" void kernel_launch(void* const* d_in, const int* in_sizes, int n_in,
                              void* d_out, int out_size, void* d_ws, size_t ws_size,
                              hipStream_t stream) {
    const float* x  = (const float*)d_in[0];
    const int*   ei = (const int*)d_in[1];
    const int*   tg = (const int*)d_in[2];
    const float* W1 = (const float*)d_in[3];
    const float* b1 = (const float*)d_in[4];
    const float* W2 = (const float*)d_in[5];
    const float* b2 = (const float*)d_in[6];
    const float* Wo = (const float*)d_in[7];
    const float* bo = (const float*)d_in[8];
    float* out = (float*)d_out;

    int n = in_sizes[0] / IN_DIM;
    int e = in_sizes[1] / 2;
    int b = in_sizes[2] / 2;
    const int* src = ei;
    const int* dst = ei + e;

    char* ws = (char*)d_ws;
    size_t off = 0;
    auto alloc = [&](size_t bytes) -> char* {
        char* p = ws + off;
        off += (bytes + 255) & ~(size_t)255;
        return p;
    };
    int*   deg       = (int*)alloc((size_t)n * 4);
    int*   row_ptr   = (int*)alloc((size_t)n * 4);
    int*   write_ptr = (int*)alloc((size_t)n * 4);
    int*   blksums   = (int*)alloc(1024 * 4);
    int*   blkoffs   = (int*)alloc(1024 * 4);
    float* dis       = (float*)alloc((size_t)n * 4);
    int*   adj       = (int*)alloc((size_t)e * 4);
    float* bufA      = (float*)alloc((size_t)n * HID * 4);  // hn, then hn2
    float* bufB      = (float*)alloc((size_t)n * HID * 4);  // h,  then z

    int nb1024 = (n + 1023) / 1024;
    int nrange = (n + NGROUP - 1) / NGROUP;
    int part_grid = 2048;   // 256 blocks per group x 8 groups

    k_init_deg<<<(n + 255) / 256, 256, 0, stream>>>(deg, n);
    k_count_part<<<part_grid, 256, 0, stream>>>(dst, deg, e, nrange, n);
    k_dis<<<(n + 255) / 256, 256, 0, stream>>>(deg, dis, n);

    k_scanA<<<nb1024, 1024, 0, stream>>>(deg, row_ptr, blksums, n);
    k_scanB<<<1, 1024, 0, stream>>>(blksums, blkoffs, nb1024);
    k_scanC<<<nb1024, 1024, 0, stream>>>(row_ptr, blkoffs, write_ptr, n);

    k_fill_part<<<part_grid, 256, 0, stream>>>(src, dst, write_ptr, adj, e, nrange, n);

    k_gemm1<<<((size_t)n * HID + 255) / 256, 256, 0, stream>>>(x, W1, dis, bufA, n);
    k_agg1<<<(n + 3) / 4, 256, 0, stream>>>(bufA, row_ptr, deg, adj, dis, b1, bufB, n);
    k_gemm2<<<((size_t)n * EMB + 255) / 256, 256, 0, stream>>>(bufB, W2, dis, bufA, n);
    k_agg2<<<(n + 3) / 4, 256, 0, stream>>>(bufA, row_ptr, deg, adj, dis, b2, bufB, n);

    k_head<<<(b + 255) / 256, 256, 0, stream>>>(bufB, tg, Wo, bo, out, b);
}

// Round 3
// 519.734 us; speedup vs baseline: 1.4445x; 1.2009x over previous
//
#include <hip/hip_runtime.h>

#define IN_DIM 18
#define HID 64
#define EMB 32
#define NGROUP 8   // XCD count; blockIdx.x & 7 ~ XCD id (heuristic, speed-only)

__device__ inline float4 shfl_xor_f4(float4 v, int m) {
    v.x = __shfl_xor(v.x, m);
    v.y = __shfl_xor(v.y, m);
    v.z = __shfl_xor(v.z, m);
    v.w = __shfl_xor(v.w, m);
    return v;
}

// ---------------- degree / normalization ----------------

__global__ void k_init_deg(int* __restrict__ deg, int n) {
    int i = blockIdx.x * 256 + threadIdx.x;
    if (i < n) deg[i] = 1;   // self-loop
}

// XCD-partitioned histogram: group g only counts dst in [lo,hi) so deg lines
// stay resident in a single XCD's L2 (no cross-XCD dirty-line ping).
__global__ void k_count_part(const int* __restrict__ dst, int* __restrict__ deg,
                             int e, int nrange, int n) {
    int g  = blockIdx.x & (NGROUP - 1);
    int lo = g * nrange;
    int hi = min(n, lo + nrange);
    int bid  = blockIdx.x >> 3;
    int nblk = gridDim.x >> 3;
    int i0   = (bid * 256 + threadIdx.x) * 4;
    int step = nblk * 256 * 4;
    for (int i = i0; i < e; i += step) {
        if (i + 4 <= e) {
            int4 d4 = *(const int4*)(dst + i);
            if (d4.x >= lo && d4.x < hi) atomicAdd(&deg[d4.x], 1);
            if (d4.y >= lo && d4.y < hi) atomicAdd(&deg[d4.y], 1);
            if (d4.z >= lo && d4.z < hi) atomicAdd(&deg[d4.z], 1);
            if (d4.w >= lo && d4.w < hi) atomicAdd(&deg[d4.w], 1);
        } else {
            for (int k = i; k < e; ++k) {
                int d = dst[k];
                if (d >= lo && d < hi) atomicAdd(&deg[d], 1);
            }
        }
    }
}

__global__ void k_dis(const int* __restrict__ deg, float* __restrict__ dis, int n) {
    int i = blockIdx.x * 256 + threadIdx.x;
    if (i < n) dis[i] = rsqrtf((float)deg[i]);
}

// ---------------- exclusive scan of counts (deg-1) -> row_ptr ----------------

__global__ void k_scanA(const int* __restrict__ deg, int* __restrict__ row_ptr,
                        int* __restrict__ blksums, int n) {
    __shared__ int s[1024];
    int tid = threadIdx.x;
    int i = blockIdx.x * 1024 + tid;
    int v = (i < n) ? (deg[i] - 1) : 0;
    s[tid] = v;
    __syncthreads();
    for (int off = 1; off < 1024; off <<= 1) {
        int t = (tid >= off) ? s[tid - off] : 0;
        __syncthreads();
        s[tid] += t;
        __syncthreads();
    }
    if (i < n) row_ptr[i] = s[tid] - v;       // exclusive within block
    if (tid == 1023) blksums[blockIdx.x] = s[1023];
}

__global__ void k_scanB(const int* __restrict__ blksums, int* __restrict__ blkoffs, int nb) {
    __shared__ int s[1024];
    int tid = threadIdx.x;
    int v = (tid < nb) ? blksums[tid] : 0;
    s[tid] = v;
    __syncthreads();
    for (int off = 1; off < 1024; off <<= 1) {
        int t = (tid >= off) ? s[tid - off] : 0;
        __syncthreads();
        s[tid] += t;
        __syncthreads();
    }
    if (tid < nb) blkoffs[tid] = s[tid] - v;  // exclusive
}

__global__ void k_scanC(int* __restrict__ row_ptr, const int* __restrict__ blkoffs,
                        int* __restrict__ write_ptr, int n) {
    int i = blockIdx.x * 1024 + threadIdx.x;
    if (i < n) {
        int r = row_ptr[i] + blkoffs[blockIdx.x];
        row_ptr[i] = r;
        write_ptr[i] = r;
    }
}

// ---------------- CSR fill (XCD-partitioned) ----------------

__global__ void k_fill_part(const int* __restrict__ src, const int* __restrict__ dst,
                            int* __restrict__ write_ptr, int* __restrict__ adj,
                            int e, int nrange, int n) {
    int g  = blockIdx.x & (NGROUP - 1);
    int lo = g * nrange;
    int hi = min(n, lo + nrange);
    int bid  = blockIdx.x >> 3;
    int nblk = gridDim.x >> 3;
    int i0   = (bid * 256 + threadIdx.x) * 4;
    int step = nblk * 256 * 4;
    for (int i = i0; i < e; i += step) {
        if (i + 4 <= e) {
            int4 d4 = *(const int4*)(dst + i);
            if (d4.x >= lo && d4.x < hi) { int slot = atomicAdd(&write_ptr[d4.x], 1); adj[slot] = src[i];     }
            if (d4.y >= lo && d4.y < hi) { int slot = atomicAdd(&write_ptr[d4.y], 1); adj[slot] = src[i + 1]; }
            if (d4.z >= lo && d4.z < hi) { int slot = atomicAdd(&write_ptr[d4.z], 1); adj[slot] = src[i + 2]; }
            if (d4.w >= lo && d4.w < hi) { int slot = atomicAdd(&write_ptr[d4.w], 1); adj[slot] = src[i + 3]; }
        } else {
            for (int k = i; k < e; ++k) {
                int d = dst[k];
                if (d >= lo && d < hi) { int slot = atomicAdd(&write_ptr[d], 1); adj[slot] = src[k]; }
            }
        }
    }
}

// ---------------- layer GEMMs (dense, tiny K) ----------------

// hn[i][f] = (x[i,:] @ W1[:,f]) * dis[i]
__global__ void k_gemm1(const float* __restrict__ x, const float* __restrict__ W1,
                        const float* __restrict__ dis, float* __restrict__ hn, int n) {
    __shared__ float w[IN_DIM * HID];
    for (int t = threadIdx.x; t < IN_DIM * HID; t += 256) w[t] = W1[t];
    __syncthreads();
    int gid = blockIdx.x * 256 + threadIdx.x;
    int i = gid >> 6, f = gid & 63;
    if (i >= n) return;
    const float* xr = x + (size_t)i * IN_DIM;
    float acc = 0.f;
#pragma unroll
    for (int k = 0; k < IN_DIM; ++k) acc += xr[k] * w[k * HID + f];
    hn[(size_t)i * HID + f] = acc * dis[i];
}

// hn2[i][g] = (h[i,:] @ W2[:,g]) * dis[i]
__global__ void k_gemm2(const float* __restrict__ h, const float* __restrict__ W2,
                        const float* __restrict__ dis, float* __restrict__ hn2, int n) {
    __shared__ float w[HID * EMB];
    for (int t = threadIdx.x; t < HID * EMB; t += 256) w[t] = W2[t];
    __syncthreads();
    int gid = blockIdx.x * 256 + threadIdx.x;
    int i = gid >> 5, g = gid & 31;
    if (i >= n) return;
    const float* hr = h + (size_t)i * HID;
    float acc = 0.f;
#pragma unroll
    for (int k = 0; k < HID; ++k) acc += hr[k] * w[k * EMB + g];
    hn2[(size_t)i * EMB + g] = acc * dis[i];
}

// ---------------- aggregation (gather over CSR, float4 per lane) ----------------

// One wave per node. HID=64 -> 16 lanes x float4 per row; 4 edge-groups,
// unrolled x2 -> 8 gathers in flight per wave.
__global__ void k_agg1(const float* __restrict__ hn, const int* __restrict__ row_ptr,
                       const int* __restrict__ deg, const int* __restrict__ adj,
                       const float* __restrict__ dis, const float* __restrict__ b1,
                       float* __restrict__ h, int n) {
    int node = blockIdx.x * 4 + (threadIdx.x >> 6);
    if (node >= n) return;
    int lane = threadIdx.x & 63;
    int eg = lane >> 4;        // edge-group 0..3
    int d4 = lane & 15;        // float4 slot within row
    int beg = row_ptr[node];
    int cnt = deg[node] - 1;
    const int* a = adj + beg;
    float4 acc = make_float4(0.f, 0.f, 0.f, 0.f);
    int base = 0;
    for (; base + 8 <= cnt; base += 8) {
        int j0 = a[base + eg];
        int j1 = a[base + 4 + eg];
        float4 v0 = *(const float4*)(hn + (size_t)j0 * HID + d4 * 4);
        float4 v1 = *(const float4*)(hn + (size_t)j1 * HID + d4 * 4);
        acc.x += v0.x + v1.x; acc.y += v0.y + v1.y;
        acc.z += v0.z + v1.z; acc.w += v0.w + v1.w;
    }
    int kk = base + eg;
    if (kk < cnt) {
        float4 v = *(const float4*)(hn + (size_t)a[kk] * HID + d4 * 4);
        acc.x += v.x; acc.y += v.y; acc.z += v.z; acc.w += v.w;
    }
    kk += 4;
    if (kk < cnt) {
        float4 v = *(const float4*)(hn + (size_t)a[kk] * HID + d4 * 4);
        acc.x += v.x; acc.y += v.y; acc.z += v.z; acc.w += v.w;
    }
    // reduce across 4 edge-groups (xor 16, 32)
    float4 t = shfl_xor_f4(acc, 16);
    acc.x += t.x; acc.y += t.y; acc.z += t.z; acc.w += t.w;
    t = shfl_xor_f4(acc, 32);
    acc.x += t.x; acc.y += t.y; acc.z += t.z; acc.w += t.w;
    if (eg == 0) {
        float4 self = *(const float4*)(hn + (size_t)node * HID + d4 * 4);
        float4 bb = *(const float4*)(b1 + d4 * 4);
        float dn = dis[node];
        float4 o;
        o.x = fmaxf(dn * (acc.x + self.x) + bb.x, 0.f);
        o.y = fmaxf(dn * (acc.y + self.y) + bb.y, 0.f);
        o.z = fmaxf(dn * (acc.z + self.z) + bb.z, 0.f);
        o.w = fmaxf(dn * (acc.w + self.w) + bb.w, 0.f);
        *(float4*)(h + (size_t)node * HID + d4 * 4) = o;
    }
}

// EMB=32 -> 8 lanes x float4 per row; 8 edge-groups, unrolled x2 -> 16 gathers
// in flight per wave.
__global__ void k_agg2(const float* __restrict__ hn2, const int* __restrict__ row_ptr,
                       const int* __restrict__ deg, const int* __restrict__ adj,
                       const float* __restrict__ dis, const float* __restrict__ b2,
                       float* __restrict__ z, int n) {
    int node = blockIdx.x * 4 + (threadIdx.x >> 6);
    if (node >= n) return;
    int lane = threadIdx.x & 63;
    int eg = lane >> 3;        // edge-group 0..7
    int d4 = lane & 7;         // float4 slot within row
    int beg = row_ptr[node];
    int cnt = deg[node] - 1;
    const int* a = adj + beg;
    float4 acc = make_float4(0.f, 0.f, 0.f, 0.f);
    int base = 0;
    for (; base + 16 <= cnt; base += 16) {
        int j0 = a[base + eg];
        int j1 = a[base + 8 + eg];
        float4 v0 = *(const float4*)(hn2 + (size_t)j0 * EMB + d4 * 4);
        float4 v1 = *(const float4*)(hn2 + (size_t)j1 * EMB + d4 * 4);
        acc.x += v0.x + v1.x; acc.y += v0.y + v1.y;
        acc.z += v0.z + v1.z; acc.w += v0.w + v1.w;
    }
    int kk = base + eg;
    if (kk < cnt) {
        float4 v = *(const float4*)(hn2 + (size_t)a[kk] * EMB + d4 * 4);
        acc.x += v.x; acc.y += v.y; acc.z += v.z; acc.w += v.w;
    }
    kk += 8;
    if (kk < cnt) {
        float4 v = *(const float4*)(hn2 + (size_t)a[kk] * EMB + d4 * 4);
        acc.x += v.x; acc.y += v.y; acc.z += v.z; acc.w += v.w;
    }
    // reduce across 8 edge-groups (xor 8, 16, 32)
    float4 t = shfl_xor_f4(acc, 8);
    acc.x += t.x; acc.y += t.y; acc.z += t.z; acc.w += t.w;
    t = shfl_xor_f4(acc, 16);
    acc.x += t.x; acc.y += t.y; acc.z += t.z; acc.w += t.w;
    t = shfl_xor_f4(acc, 32);
    acc.x += t.x; acc.y += t.y; acc.z += t.z; acc.w += t.w;
    if (eg == 0) {
        float4 self = *(const float4*)(hn2 + (size_t)node * EMB + d4 * 4);
        float4 bb = *(const float4*)(b2 + d4 * 4);
        float dn = dis[node];
        float4 o;
        o.x = dn * (acc.x + self.x) + bb.x;
        o.y = dn * (acc.y + self.y) + bb.y;
        o.z = dn * (acc.z + self.z) + bb.z;
        o.w = dn * (acc.w + self.w) + bb.w;
        *(float4*)(z + (size_t)node * EMB + d4 * 4) = o;
    }
}

// ---------------- pair head ----------------

__global__ void k_head(const float* __restrict__ z, const int* __restrict__ tg,
                       const float* __restrict__ Wo, const float* __restrict__ bo,
                       float* __restrict__ out, int btot) {
    int i = blockIdx.x * 256 + threadIdx.x;
    if (i >= btot) return;
    int t0 = tg[i], t1 = tg[btot + i];
    const float* z0 = z + (size_t)t0 * EMB;
    const float* z1 = z + (size_t)t1 * EMB;
    float acc = 0.f;
#pragma unroll
    for (int g = 0; g < EMB; ++g) acc += z0[g] * z1[g] * Wo[g];
    out[i] = acc + bo[0];
}

// ---------------- launch ----------------

extern "C" void kernel_launch(void* const* d_in, const int* in_sizes, int n_in,
                              void* d_out, int out_size, void* d_ws, size_t ws_size,
                              hipStream_t stream) {
    const float* x  = (const float*)d_in[0];
    const int*   ei = (const int*)d_in[1];
    const int*   tg = (const int*)d_in[2];
    const float* W1 = (const float*)d_in[3];
    const float* b1 = (const float*)d_in[4];
    const float* W2 = (const float*)d_in[5];
    const float* b2 = (const float*)d_in[6];
    const float* Wo = (const float*)d_in[7];
    const float* bo = (const float*)d_in[8];
    float* out = (float*)d_out;

    int n = in_sizes[0] / IN_DIM;
    int e = in_sizes[1] / 2;
    int b = in_sizes[2] / 2;
    const int* src = ei;
    const int* dst = ei + e;

    char* ws = (char*)d_ws;
    size_t off = 0;
    auto alloc = [&](size_t bytes) -> char* {
        char* p = ws + off;
        off += (bytes + 255) & ~(size_t)255;
        return p;
    };
    int*   deg       = (int*)alloc((size_t)n * 4);
    int*   row_ptr   = (int*)alloc((size_t)n * 4);
    int*   write_ptr = (int*)alloc((size_t)n * 4);
    int*   blksums   = (int*)alloc(1024 * 4);
    int*   blkoffs   = (int*)alloc(1024 * 4);
    float* dis       = (float*)alloc((size_t)n * 4);
    int*   adj       = (int*)alloc((size_t)e * 4);
    float* bufA      = (float*)alloc((size_t)n * HID * 4);  // hn, then hn2
    float* bufB      = (float*)alloc((size_t)n * HID * 4);  // h,  then z

    int nb1024 = (n + 1023) / 1024;
    int nrange = (n + NGROUP - 1) / NGROUP;
    int part_grid = 2048;   // 256 blocks per group x 8 groups

    k_init_deg<<<(n + 255) / 256, 256, 0, stream>>>(deg, n);
    k_count_part<<<part_grid, 256, 0, stream>>>(dst, deg, e, nrange, n);
    k_dis<<<(n + 255) / 256, 256, 0, stream>>>(deg, dis, n);

    k_scanA<<<nb1024, 1024, 0, stream>>>(deg, row_ptr, blksums, n);
    k_scanB<<<1, 1024, 0, stream>>>(blksums, blkoffs, nb1024);
    k_scanC<<<nb1024, 1024, 0, stream>>>(row_ptr, blkoffs, write_ptr, n);

    k_fill_part<<<part_grid, 256, 0, stream>>>(src, dst, write_ptr, adj, e, nrange, n);

    k_gemm1<<<((size_t)n * HID + 255) / 256, 256, 0, stream>>>(x, W1, dis, bufA, n);
    k_agg1<<<(n + 3) / 4, 256, 0, stream>>>(bufA, row_ptr, deg, adj, dis, b1, bufB, n);
    k_gemm2<<<((size_t)n * EMB + 255) / 256, 256, 0, stream>>>(bufB, W2, dis, bufA, n);
    k_agg2<<<(n + 3) / 4, 256, 0, stream>>>(bufA, row_ptr, deg, adj, dis, b2, bufB, n);

    k_head<<<(b + 255) / 256, 256, 0, stream>>>(bufB, tg, Wo, bo, out, b);
}